// Round 1
// baseline (558.668 us; speedup 1.0000x reference)
//
#include <hip/hip_runtime.h>
#include <math.h>

#define RFL(x) __builtin_amdgcn_readfirstlane(x)

// LIF: v = v + (x - v)/2 ; s = (v >= 1) ; v = s ? 0 : v   (exact rounding match, no contraction)
static __device__ __forceinline__ float lif_upd(float& v, float x) {
  v = __fadd_rn(v, __fmul_rn(__fsub_rn(x, v), 0.5f));
  float s = (v >= 1.0f) ? 1.0f : 0.0f;
  v = (v >= 1.0f) ? 0.0f : v;
  return s;
}

__global__ __launch_bounds__(256) void k_zero(float4* __restrict__ p, int n4) {
  int i = blockIdx.x * 256 + threadIdx.x;
  int stride = gridDim.x * 256;
  for (; i < n4; i += stride) p[i] = make_float4(0.f, 0.f, 0.f, 0.f);
}

// Layer 0: fused conv(2->64, 128x128, SAME) + BN + LIF + 2x2 maxpool.
// 1 pooled output per thread; t-loop internal, membrane v in registers.
// out: padded spikes [4][8][64][66][66] (interior at +1,+1)
__global__ __launch_bounds__(256) void k_conv0(
    const float* __restrict__ x,   // [8][4][2][128][128]
    const float* __restrict__ w,   // [64][2][3][3]
    const float* __restrict__ bng, const float* __restrict__ bnb,
    const float* __restrict__ bnm, const float* __restrict__ bnv,
    float* __restrict__ out)
{
  int id = blockIdx.x * 256 + threadIdx.x;
  int pp = id & 4095;              // 64x64 pooled positions
  int co = RFL((id >> 12) & 63);
  int n  = RFL(id >> 18);
  int py = pp >> 6, px = pp & 63;

  float inv  = 1.0f / sqrtf(bnv[co] + 1e-5f);
  float gsc  = __fmul_rn(bng[co], inv);
  float bias = __fsub_rn(bnb[co], __fmul_rn(__fmul_rn(bnm[co], bng[co]), inv));

  float vm0 = 0.f, vm1 = 0.f, vm2 = 0.f, vm3 = 0.f;
  #pragma unroll 1
  for (int t = 0; t < 4; ++t) {
    float s00 = 0.f, s01 = 0.f, s10 = 0.f, s11 = 0.f;
    #pragma unroll
    for (int ci = 0; ci < 2; ++ci) {
      const float* pl = x + ((n * 4 + t) * 2 + ci) * 16384;
      const float* wp = w + co * 18 + ci * 9;
      float p[4][4];
      #pragma unroll
      for (int i = 0; i < 4; ++i) {
        int r = 2 * py - 1 + i;
        bool rv = (unsigned)r < 128u;
        #pragma unroll
        for (int j = 0; j < 4; ++j) {
          int c = 2 * px - 1 + j;
          p[i][j] = (rv && ((unsigned)c < 128u)) ? pl[r * 128 + c] : 0.f;
        }
      }
      #pragma unroll
      for (int ky = 0; ky < 3; ++ky)
        #pragma unroll
        for (int kx = 0; kx < 3; ++kx) {
          float wv = wp[ky * 3 + kx];
          s00 = fmaf(p[ky    ][kx    ], wv, s00);
          s01 = fmaf(p[ky    ][kx + 1], wv, s01);
          s10 = fmaf(p[ky + 1][kx    ], wv, s10);
          s11 = fmaf(p[ky + 1][kx + 1], wv, s11);
        }
    }
    float h00 = __fadd_rn(__fmul_rn(s00, gsc), bias);
    float h01 = __fadd_rn(__fmul_rn(s01, gsc), bias);
    float h10 = __fadd_rn(__fmul_rn(s10, gsc), bias);
    float h11 = __fadd_rn(__fmul_rn(s11, gsc), bias);
    float sp = fmaxf(fmaxf(lif_upd(vm0, h00), lif_upd(vm1, h01)),
                     fmaxf(lif_upd(vm2, h10), lif_upd(vm3, h11)));
    out[(((t * 8 + n) * 64 + co) * 66 + (py + 1)) * 66 + (px + 1)] = sp;
  }
}

// Conv (64->64, HxH, SAME) + BN, t-parallel. Reads padded spikes, writes pre-activation.
// TPxTP conv pixels per thread (register tile). Weights are wave-uniform -> scalar loads.
template<int H, int TP>
__global__ __launch_bounds__(256) void k_conv(
    const float* __restrict__ in,   // [4][8][64][H+2][H+2] padded spikes
    const float* __restrict__ w,    // [64][64][3][3] (layer slice)
    const float* __restrict__ bng, const float* __restrict__ bnb,
    const float* __restrict__ bnm, const float* __restrict__ bnv,
    float* __restrict__ pre)        // [4][8][64][H][H]
{
  constexpr int W2 = H + 2;
  constexpr int TX = H / TP;
  constexpr int TILES = TX * TX;
  constexpr int K = 4 * TILES;      // (t, tile) per (n, co); multiple of 64 -> co wave-uniform
  int id = blockIdx.x * 256 + threadIdx.x;
  int k  = id % K;
  int co = RFL((id / K) & 63);
  int n  = RFL(id / (K * 64));
  int t    = k / TILES;
  int tile = k % TILES;
  int y0 = (tile / TX) * TP;
  int x0 = (tile % TX) * TP;

  float inv  = 1.0f / sqrtf(bnv[co] + 1e-5f);
  float gsc  = __fmul_rn(bng[co], inv);
  float bias = __fsub_rn(bnb[co], __fmul_rn(__fmul_rn(bnm[co], bng[co]), inv));

  const float* wb = w + co * 576;
  const float* ib = in + ((t * 8 + n) * 64) * (W2 * W2) + y0 * W2 + x0;

  float acc[TP * TP];
  #pragma unroll
  for (int q = 0; q < TP * TP; ++q) acc[q] = 0.f;

  #pragma unroll 1
  for (int ci = 0; ci < 64; ++ci) {
    const float* pl = ib + ci * (W2 * W2);
    float p[TP + 2][TP + 2];
    #pragma unroll
    for (int i = 0; i < TP + 2; ++i)
      #pragma unroll
      for (int j = 0; j < TP + 2; ++j)
        p[i][j] = pl[i * W2 + j];
    const float* wp = wb + ci * 9;
    #pragma unroll
    for (int ky = 0; ky < 3; ++ky)
      #pragma unroll
      for (int kx = 0; kx < 3; ++kx) {
        float wv = wp[ky * 3 + kx];
        #pragma unroll
        for (int a = 0; a < TP; ++a)
          #pragma unroll
          for (int b = 0; b < TP; ++b)
            acc[a * TP + b] = fmaf(p[a + ky][b + kx], wv, acc[a * TP + b]);
      }
  }
  float* ob = pre + ((t * 8 + n) * 64 + co) * (H * H) + y0 * H + x0;
  #pragma unroll
  for (int a = 0; a < TP; ++a)
    #pragma unroll
    for (int b = 0; b < TP; ++b)
      ob[a * H + b] = __fadd_rn(__fmul_rn(acc[a * TP + b], gsc), bias);
}

// LIF (t-sequential, v in registers) + 2x2 maxpool over pre-activations.
template<int H, bool PADOUT>
__global__ __launch_bounds__(256) void k_lifpool(
    const float* __restrict__ pre,  // [4][8][64][H][H]
    float* __restrict__ out)        // PADOUT: [4][8][64][H/2+2][H/2+2] else flat [4][8][64][H/2][H/2]
{
  constexpr int Hp = H / 2;
  constexpr int PP = Hp * Hp;
  int id = blockIdx.x * 256 + threadIdx.x;
  int pp = id % PP;
  int co = (id / PP) & 63;
  int n  = id / (PP * 64);
  int py = pp / Hp, px = pp % Hp;
  float v0 = 0.f, v1 = 0.f, v2 = 0.f, v3 = 0.f;
  #pragma unroll 1
  for (int t = 0; t < 4; ++t) {
    const float* pb = pre + ((t * 8 + n) * 64 + co) * (H * H) + (2 * py) * H + 2 * px;
    float sp = fmaxf(fmaxf(lif_upd(v0, pb[0]), lif_upd(v1, pb[1])),
                     fmaxf(lif_upd(v2, pb[H]), lif_upd(v3, pb[H + 1])));
    if (PADOUT)
      out[(((t * 8 + n) * 64 + co) * (Hp + 2) + (py + 1)) * (Hp + 2) + (px + 1)] = sp;
    else
      out[((t * 8 + n) * 64 + co) * PP + pp] = sp;
  }
}

// FC1: (8,1024)@(256,1024)^T + LIF, one wave per (n,j), weights cached in 16 regs across t.
__global__ __launch_bounds__(256) void k_fc1(
    const float* __restrict__ s4, const float* __restrict__ w, float* __restrict__ out)
{
  int wv = blockIdx.x * 4 + (threadIdx.x >> 6);
  int lane = threadIdx.x & 63;
  int j = wv & 255;
  int n = wv >> 8;
  float wr[16];
  #pragma unroll
  for (int u = 0; u < 16; ++u) wr[u] = w[j * 1024 + u * 64 + lane];
  float v = 0.f;
  #pragma unroll 1
  for (int t = 0; t < 4; ++t) {
    const float* sp = s4 + (t * 8 + n) * 1024;
    float sum = 0.f;
    #pragma unroll
    for (int u = 0; u < 16; ++u) sum = fmaf(wr[u], sp[u * 64 + lane], sum);
    #pragma unroll
    for (int off = 32; off > 0; off >>= 1) sum += __shfl_xor(sum, off, 64);
    float s = lif_upd(v, sum);   // sum identical across lanes -> v identical
    if (lane == 0) out[(t * 8 + n) * 256 + j] = s;
  }
}

// FC2: (8,256)@(110,256)^T + LIF.
__global__ __launch_bounds__(256) void k_fc2(
    const float* __restrict__ s1, const float* __restrict__ w, float* __restrict__ out)
{
  int wv = blockIdx.x * 4 + (threadIdx.x >> 6);
  int lane = threadIdx.x & 63;
  int j = wv % 110;
  int n = wv / 110;
  float wr[4];
  #pragma unroll
  for (int u = 0; u < 4; ++u) wr[u] = w[j * 256 + u * 64 + lane];
  float v = 0.f;
  #pragma unroll 1
  for (int t = 0; t < 4; ++t) {
    const float* sp = s1 + (t * 8 + n) * 256;
    float sum = 0.f;
    #pragma unroll
    for (int u = 0; u < 4; ++u) sum = fmaf(wr[u], sp[u * 64 + lane], sum);
    #pragma unroll
    for (int off = 32; off > 0; off >>= 1) sum += __shfl_xor(sum, off, 64);
    float s = lif_upd(v, sum);
    if (lane == 0) out[(t * 8 + n) * 110 + j] = s;
  }
}

// acc[n][g] = sum_t mean_{j<10} s2[t][n][g*10+j]
__global__ __launch_bounds__(128) void k_acc(const float* __restrict__ s2, float* __restrict__ out) {
  int id = threadIdx.x;
  if (id >= 88) return;
  int n = id / 11, g = id % 11;
  float a = 0.f;
  #pragma unroll 1
  for (int t = 0; t < 4; ++t) {
    float m = 0.f;
    #pragma unroll
    for (int jj = 0; jj < 10; ++jj) m = __fadd_rn(m, s2[(t * 8 + n) * 110 + g * 10 + jj]);
    a = __fadd_rn(a, __fdiv_rn(m, 10.0f));
  }
  out[n * 11 + g] = a;
}

extern "C" void kernel_launch(void* const* d_in, const int* in_sizes, int n_in,
                              void* d_out, int out_size, void* d_ws, size_t ws_size,
                              hipStream_t stream)
{
  const float* x  = (const float*)d_in[0];
  const float* w0 = (const float*)d_in[1];
  const float* wc = (const float*)d_in[2];
  const float* bg = (const float*)d_in[3];
  const float* bb = (const float*)d_in[4];
  const float* bm = (const float*)d_in[5];
  const float* bv = (const float*)d_in[6];
  const float* w1 = (const float*)d_in[7];
  const float* w2 = (const float*)d_in[8];
  float* out = (float*)d_out;
  float* ws  = (float*)d_ws;

  // workspace layout (float offsets); padded spike buffers first (zeroed for halos)
  float* buf0 = ws + 0;         // [4][8][64][66][66] = 8,921,088
  float* buf1 = ws + 8921088;   // [4][8][64][34][34] = 2,367,488
  float* buf2 = ws + 11288576;  // [4][8][64][18][18] =   663,552
  float* buf3 = ws + 11952128;  // [4][8][64][10][10] =   204,800
  float* buf4 = ws + 12156928;  // [4][8][1024]       =    32,768  (flat, fc input)
  float* pre1 = ws + 12189696;  // [4][8][64][64][64] = 8,388,608
  float* pre2 = ws + 20578304;  // [4][8][64][32][32] = 2,097,152
  float* pre3 = ws + 22675456;  // [4][8][64][16][16] =   524,288
  float* pre4 = ws + 23199744;  // [4][8][64][8][8]   =   131,072
  float* s1   = ws + 23330816;  // [4][8][256]        =     8,192
  float* s2   = ws + 23339008;  // [4][8][110]        =     3,520
  if (ws_size < (size_t)23342528 * sizeof(float)) return;  // need ~93.4 MB

  k_zero<<<2048, 256, 0, stream>>>((float4*)ws, 12156928 / 4);  // halo zeros for buf0..buf3

  k_conv0<<<8192, 256, 0, stream>>>(x, w0, bg, bb, bm, bv, buf0);

  k_conv<64, 4><<<2048, 256, 0, stream>>>(buf0, wc + 0 * 36864, bg + 64,  bb + 64,  bm + 64,  bv + 64,  pre1);
  k_lifpool<64, true><<<2048, 256, 0, stream>>>(pre1, buf1);

  k_conv<32, 4><<<512, 256, 0, stream>>>(buf1, wc + 1 * 36864, bg + 128, bb + 128, bm + 128, bv + 128, pre2);
  k_lifpool<32, true><<<512, 256, 0, stream>>>(pre2, buf2);

  k_conv<16, 4><<<128, 256, 0, stream>>>(buf2, wc + 2 * 36864, bg + 192, bb + 192, bm + 192, bv + 192, pre3);
  k_lifpool<16, true><<<128, 256, 0, stream>>>(pre3, buf3);

  k_conv<8, 2><<<128, 256, 0, stream>>>(buf3, wc + 3 * 36864, bg + 256, bb + 256, bm + 256, bv + 256, pre4);
  k_lifpool<8, false><<<32, 256, 0, stream>>>(pre4, buf4);

  k_fc1<<<512, 256, 0, stream>>>(buf4, w1, s1);
  k_fc2<<<220, 256, 0, stream>>>(s1, w2, s2);
  k_acc<<<1, 128, 0, stream>>>(s2, out);
}

// Round 2
// 330.983 us; speedup vs baseline: 1.6879x; 1.6879x over previous
//
#include <hip/hip_runtime.h>
#include <math.h>

#define RFL(x) __builtin_amdgcn_readfirstlane(x)

// LIF: v = v + (x - v)/2 ; s = (v >= 1) ; v = s ? 0 : v   (exact rounding match, no contraction)
static __device__ __forceinline__ float lif_upd(float& v, float x) {
  v = __fadd_rn(v, __fmul_rn(__fsub_rn(x, v), 0.5f));
  float s = (v >= 1.0f) ? 1.0f : 0.0f;
  v = (v >= 1.0f) ? 0.0f : v;
  return s;
}

__global__ __launch_bounds__(256) void k_zero(float4* __restrict__ p, int n4) {
  int i = blockIdx.x * 256 + threadIdx.x;
  int stride = gridDim.x * 256;
  for (; i < n4; i += stride) p[i] = make_float4(0.f, 0.f, 0.f, 0.f);
}

// Layer 0: fused conv(2->64, 128x128, SAME) + BN + LIF + 2x2 maxpool.
// co-blocked: 4 output channels x 1 pooled px per thread; t-loop internal, v in regs.
// out: padded spikes [4][8][64][66][66] (interior at +1,+1)
__global__ __launch_bounds__(256, 4) void k_conv0(
    const float* __restrict__ x,   // [8][4][2][128][128]
    const float* __restrict__ w,   // [64][2][3][3]
    const float* __restrict__ bng, const float* __restrict__ bnb,
    const float* __restrict__ bnm, const float* __restrict__ bnv,
    float* __restrict__ out)
{
  int id = blockIdx.x * 256 + threadIdx.x;
  int pp  = id & 4095;             // 64x64 pooled positions
  int cog = RFL((id >> 12) & 15);  // 4-channel group
  int n   = RFL(id >> 16);
  int py = pp >> 6, px = pp & 63;

  float gsc[4], bias[4];
  #pragma unroll
  for (int j = 0; j < 4; ++j) {
    int co = cog * 4 + j;
    float inv = 1.0f / sqrtf(bnv[co] + 1e-5f);
    gsc[j]  = __fmul_rn(bng[co], inv);
    bias[j] = __fsub_rn(bnb[co], __fmul_rn(__fmul_rn(bnm[co], bng[co]), inv));
  }

  float vm[4][4];
  #pragma unroll
  for (int j = 0; j < 4; ++j)
    #pragma unroll
    for (int q = 0; q < 4; ++q) vm[j][q] = 0.f;

  #pragma unroll 1
  for (int t = 0; t < 4; ++t) {
    float s[4][4];
    #pragma unroll
    for (int j = 0; j < 4; ++j)
      #pragma unroll
      for (int q = 0; q < 4; ++q) s[j][q] = 0.f;

    #pragma unroll
    for (int ci = 0; ci < 2; ++ci) {
      const float* pl = x + ((n * 4 + t) * 2 + ci) * 16384;
      float p[4][4];
      #pragma unroll
      for (int i = 0; i < 4; ++i) {
        int r = 2 * py - 1 + i;
        bool rv = (unsigned)r < 128u;
        #pragma unroll
        for (int jj = 0; jj < 4; ++jj) {
          int c = 2 * px - 1 + jj;
          p[i][jj] = (rv && ((unsigned)c < 128u)) ? pl[r * 128 + c] : 0.f;
        }
      }
      #pragma unroll
      for (int j = 0; j < 4; ++j) {
        const float* wp = w + (cog * 4 + j) * 18 + ci * 9;
        #pragma unroll
        for (int ky = 0; ky < 3; ++ky)
          #pragma unroll
          for (int kx = 0; kx < 3; ++kx) {
            float wv = wp[ky * 3 + kx];
            s[j][0] = fmaf(p[ky    ][kx    ], wv, s[j][0]);
            s[j][1] = fmaf(p[ky    ][kx + 1], wv, s[j][1]);
            s[j][2] = fmaf(p[ky + 1][kx    ], wv, s[j][2]);
            s[j][3] = fmaf(p[ky + 1][kx + 1], wv, s[j][3]);
          }
      }
    }
    #pragma unroll
    for (int j = 0; j < 4; ++j) {
      float h0 = __fadd_rn(__fmul_rn(s[j][0], gsc[j]), bias[j]);
      float h1 = __fadd_rn(__fmul_rn(s[j][1], gsc[j]), bias[j]);
      float h2 = __fadd_rn(__fmul_rn(s[j][2], gsc[j]), bias[j]);
      float h3 = __fadd_rn(__fmul_rn(s[j][3], gsc[j]), bias[j]);
      float sp = fmaxf(fmaxf(lif_upd(vm[j][0], h0), lif_upd(vm[j][1], h1)),
                       fmaxf(lif_upd(vm[j][2], h2), lif_upd(vm[j][3], h3)));
      out[(((t * 8 + n) * 64 + cog * 4 + j) * 66 + (py + 1)) * 66 + (px + 1)] = sp;
    }
  }
}

// Conv (64->64, HxH, SAME) + BN, t-parallel, co-blocked.
// CO_B output channels x TPYxTPX pixels per thread. Weights wave-uniform -> scalar loads.
// Requires TILES = (H/TPY)*(H/TPX) to be a multiple of 64.
template<int H, int CO_B, int TPY, int TPX>
__global__ __launch_bounds__(256, 4) void k_convB(
    const float* __restrict__ in,   // [4][8][64][H+2][H+2] padded spikes
    const float* __restrict__ w,    // [64][64][3][3] (layer slice)
    const float* __restrict__ bng, const float* __restrict__ bnb,
    const float* __restrict__ bnm, const float* __restrict__ bnv,
    float* __restrict__ pre)        // [4][8][64][H][H]
{
  constexpr int W2 = H + 2;
  constexpr int TX = H / TPX;
  constexpr int TY = H / TPY;
  constexpr int TILES = TX * TY;
  constexpr int NCOG = 64 / CO_B;

  int id = blockIdx.x * 256 + threadIdx.x;
  int tile = id % TILES;
  int rest = id / TILES;
  int cog = RFL(rest % NCOG);
  int t   = RFL((rest / NCOG) & 3);
  int n   = RFL(rest / (NCOG * 4));
  int tx = tile % TX, ty = tile / TX;
  int x0 = tx * TPX, y0 = ty * TPY;

  float gsc[CO_B], bias[CO_B];
  #pragma unroll
  for (int j = 0; j < CO_B; ++j) {
    int co = cog * CO_B + j;
    float inv = 1.0f / sqrtf(bnv[co] + 1e-5f);
    gsc[j]  = __fmul_rn(bng[co], inv);
    bias[j] = __fsub_rn(bnb[co], __fmul_rn(__fmul_rn(bnm[co], bng[co]), inv));
  }

  const float* ib = in + ((t * 8 + n) * 64) * (W2 * W2) + y0 * W2 + x0;
  const float* wb = w + (cog * CO_B) * 576;

  float acc[CO_B][TPY * TPX];
  #pragma unroll
  for (int j = 0; j < CO_B; ++j)
    #pragma unroll
    for (int q = 0; q < TPY * TPX; ++q) acc[j][q] = 0.f;

  #pragma unroll 1
  for (int ci = 0; ci < 64; ++ci) {
    const float* pl = ib + ci * (W2 * W2);
    float p[TPY + 2][TPX + 2];
    #pragma unroll
    for (int i = 0; i < TPY + 2; ++i)
      #pragma unroll
      for (int jj = 0; jj < TPX + 2; ++jj)
        p[i][jj] = pl[i * W2 + jj];
    #pragma unroll
    for (int j = 0; j < CO_B; ++j) {
      const float* wp = wb + j * 576 + ci * 9;
      #pragma unroll
      for (int ky = 0; ky < 3; ++ky)
        #pragma unroll
        for (int kx = 0; kx < 3; ++kx) {
          float wv = wp[ky * 3 + kx];
          #pragma unroll
          for (int a = 0; a < TPY; ++a)
            #pragma unroll
            for (int b = 0; b < TPX; ++b)
              acc[j][a * TPX + b] = fmaf(p[a + ky][b + kx], wv, acc[j][a * TPX + b]);
        }
    }
  }
  #pragma unroll
  for (int j = 0; j < CO_B; ++j) {
    float* ob = pre + ((t * 8 + n) * 64 + cog * CO_B + j) * (H * H) + y0 * H + x0;
    #pragma unroll
    for (int a = 0; a < TPY; ++a)
      #pragma unroll
      for (int b = 0; b < TPX; ++b)
        ob[a * H + b] = __fadd_rn(__fmul_rn(acc[j][a * TPX + b], gsc[j]), bias[j]);
  }
}

// Old-style conv for H=8 (TILES=16 -> K=64 keeps co wave-uniform).
template<int H, int TP>
__global__ __launch_bounds__(256) void k_conv(
    const float* __restrict__ in, const float* __restrict__ w,
    const float* __restrict__ bng, const float* __restrict__ bnb,
    const float* __restrict__ bnm, const float* __restrict__ bnv,
    float* __restrict__ pre)
{
  constexpr int W2 = H + 2;
  constexpr int TX = H / TP;
  constexpr int TILES = TX * TX;
  constexpr int K = 4 * TILES;
  int id = blockIdx.x * 256 + threadIdx.x;
  int k  = id % K;
  int co = RFL((id / K) & 63);
  int n  = RFL(id / (K * 64));
  int t    = k / TILES;
  int tile = k % TILES;
  int y0 = (tile / TX) * TP;
  int x0 = (tile % TX) * TP;

  float inv  = 1.0f / sqrtf(bnv[co] + 1e-5f);
  float gsc  = __fmul_rn(bng[co], inv);
  float bias = __fsub_rn(bnb[co], __fmul_rn(__fmul_rn(bnm[co], bng[co]), inv));

  const float* wb = w + co * 576;
  const float* ib = in + ((t * 8 + n) * 64) * (W2 * W2) + y0 * W2 + x0;

  float acc[TP * TP];
  #pragma unroll
  for (int q = 0; q < TP * TP; ++q) acc[q] = 0.f;

  #pragma unroll 1
  for (int ci = 0; ci < 64; ++ci) {
    const float* pl = ib + ci * (W2 * W2);
    float p[TP + 2][TP + 2];
    #pragma unroll
    for (int i = 0; i < TP + 2; ++i)
      #pragma unroll
      for (int j = 0; j < TP + 2; ++j)
        p[i][j] = pl[i * W2 + j];
    const float* wp = wb + ci * 9;
    #pragma unroll
    for (int ky = 0; ky < 3; ++ky)
      #pragma unroll
      for (int kx = 0; kx < 3; ++kx) {
        float wv = wp[ky * 3 + kx];
        #pragma unroll
        for (int a = 0; a < TP; ++a)
          #pragma unroll
          for (int b = 0; b < TP; ++b)
            acc[a * TP + b] = fmaf(p[a + ky][b + kx], wv, acc[a * TP + b]);
      }
  }
  float* ob = pre + ((t * 8 + n) * 64 + co) * (H * H) + y0 * H + x0;
  #pragma unroll
  for (int a = 0; a < TP; ++a)
    #pragma unroll
    for (int b = 0; b < TP; ++b)
      ob[a * H + b] = __fadd_rn(__fmul_rn(acc[a * TP + b], gsc), bias);
}

// LIF (t-sequential, v in registers) + 2x2 maxpool over pre-activations.
template<int H, bool PADOUT>
__global__ __launch_bounds__(256) void k_lifpool(
    const float* __restrict__ pre,  // [4][8][64][H][H]
    float* __restrict__ out)        // PADOUT: [4][8][64][H/2+2][H/2+2] else flat
{
  constexpr int Hp = H / 2;
  constexpr int PP = Hp * Hp;
  int id = blockIdx.x * 256 + threadIdx.x;
  int pp = id % PP;
  int co = (id / PP) & 63;
  int n  = id / (PP * 64);
  int py = pp / Hp, px = pp % Hp;
  float v0 = 0.f, v1 = 0.f, v2 = 0.f, v3 = 0.f;
  #pragma unroll 1
  for (int t = 0; t < 4; ++t) {
    const float* pb = pre + ((t * 8 + n) * 64 + co) * (H * H) + (2 * py) * H + 2 * px;
    float sp = fmaxf(fmaxf(lif_upd(v0, pb[0]), lif_upd(v1, pb[1])),
                     fmaxf(lif_upd(v2, pb[H]), lif_upd(v3, pb[H + 1])));
    if (PADOUT)
      out[(((t * 8 + n) * 64 + co) * (Hp + 2) + (py + 1)) * (Hp + 2) + (px + 1)] = sp;
    else
      out[((t * 8 + n) * 64 + co) * PP + pp] = sp;
  }
}

// FC1: (8,1024)@(256,1024)^T + LIF, one wave per (n,j), weights cached in 16 regs across t.
__global__ __launch_bounds__(256) void k_fc1(
    const float* __restrict__ s4, const float* __restrict__ w, float* __restrict__ out)
{
  int wv = blockIdx.x * 4 + (threadIdx.x >> 6);
  int lane = threadIdx.x & 63;
  int j = wv & 255;
  int n = wv >> 8;
  float wr[16];
  #pragma unroll
  for (int u = 0; u < 16; ++u) wr[u] = w[j * 1024 + u * 64 + lane];
  float v = 0.f;
  #pragma unroll 1
  for (int t = 0; t < 4; ++t) {
    const float* sp = s4 + (t * 8 + n) * 1024;
    float sum = 0.f;
    #pragma unroll
    for (int u = 0; u < 16; ++u) sum = fmaf(wr[u], sp[u * 64 + lane], sum);
    #pragma unroll
    for (int off = 32; off > 0; off >>= 1) sum += __shfl_xor(sum, off, 64);
    float s = lif_upd(v, sum);
    if (lane == 0) out[(t * 8 + n) * 256 + j] = s;
  }
}

// FC2: (8,256)@(110,256)^T + LIF.
__global__ __launch_bounds__(256) void k_fc2(
    const float* __restrict__ s1, const float* __restrict__ w, float* __restrict__ out)
{
  int wv = blockIdx.x * 4 + (threadIdx.x >> 6);
  int lane = threadIdx.x & 63;
  int j = wv % 110;
  int n = wv / 110;
  float wr[4];
  #pragma unroll
  for (int u = 0; u < 4; ++u) wr[u] = w[j * 256 + u * 64 + lane];
  float v = 0.f;
  #pragma unroll 1
  for (int t = 0; t < 4; ++t) {
    const float* sp = s1 + (t * 8 + n) * 256;
    float sum = 0.f;
    #pragma unroll
    for (int u = 0; u < 4; ++u) sum = fmaf(wr[u], sp[u * 64 + lane], sum);
    #pragma unroll
    for (int off = 32; off > 0; off >>= 1) sum += __shfl_xor(sum, off, 64);
    float s = lif_upd(v, sum);
    if (lane == 0) out[(t * 8 + n) * 110 + j] = s;
  }
}

// acc[n][g] = sum_t mean_{j<10} s2[t][n][g*10+j]
__global__ __launch_bounds__(128) void k_acc(const float* __restrict__ s2, float* __restrict__ out) {
  int id = threadIdx.x;
  if (id >= 88) return;
  int n = id / 11, g = id % 11;
  float a = 0.f;
  #pragma unroll 1
  for (int t = 0; t < 4; ++t) {
    float m = 0.f;
    #pragma unroll
    for (int jj = 0; jj < 10; ++jj) m = __fadd_rn(m, s2[(t * 8 + n) * 110 + g * 10 + jj]);
    a = __fadd_rn(a, __fdiv_rn(m, 10.0f));
  }
  out[n * 11 + g] = a;
}

extern "C" void kernel_launch(void* const* d_in, const int* in_sizes, int n_in,
                              void* d_out, int out_size, void* d_ws, size_t ws_size,
                              hipStream_t stream)
{
  const float* x  = (const float*)d_in[0];
  const float* w0 = (const float*)d_in[1];
  const float* wc = (const float*)d_in[2];
  const float* bg = (const float*)d_in[3];
  const float* bb = (const float*)d_in[4];
  const float* bm = (const float*)d_in[5];
  const float* bv = (const float*)d_in[6];
  const float* w1 = (const float*)d_in[7];
  const float* w2 = (const float*)d_in[8];
  float* out = (float*)d_out;
  float* ws  = (float*)d_ws;

  // workspace layout (float offsets); padded spike buffers first (zeroed for halos)
  float* buf0 = ws + 0;         // [4][8][64][66][66] = 8,921,088
  float* buf1 = ws + 8921088;   // [4][8][64][34][34] = 2,367,488
  float* buf2 = ws + 11288576;  // [4][8][64][18][18] =   663,552
  float* buf3 = ws + 11952128;  // [4][8][64][10][10] =   204,800
  float* buf4 = ws + 12156928;  // [4][8][1024]       =    32,768  (flat, fc input)
  float* pre1 = ws + 12189696;  // [4][8][64][64][64] = 8,388,608
  float* pre2 = ws + 20578304;  // [4][8][64][32][32] = 2,097,152
  float* pre3 = ws + 22675456;  // [4][8][64][16][16] =   524,288
  float* pre4 = ws + 23199744;  // [4][8][64][8][8]   =   131,072
  float* s1   = ws + 23330816;  // [4][8][256]        =     8,192
  float* s2   = ws + 23339008;  // [4][8][110]        =     3,520
  if (ws_size < (size_t)23342528 * sizeof(float)) return;  // need ~93.4 MB

  k_zero<<<2048, 256, 0, stream>>>((float4*)ws, 12156928 / 4);  // halo zeros for buf0..buf3

  k_conv0<<<2048, 256, 0, stream>>>(x, w0, bg, bb, bm, bv, buf0);

  k_convB<64, 4, 4, 2><<<1024, 256, 0, stream>>>(buf0, wc + 0 * 36864, bg + 64,  bb + 64,  bm + 64,  bv + 64,  pre1);
  k_lifpool<64, true><<<2048, 256, 0, stream>>>(pre1, buf1);

  k_convB<32, 4, 4, 2><<<256, 256, 0, stream>>>(buf1, wc + 1 * 36864, bg + 128, bb + 128, bm + 128, bv + 128, pre2);
  k_lifpool<32, true><<<512, 256, 0, stream>>>(pre2, buf2);

  k_convB<16, 4, 2, 2><<<128, 256, 0, stream>>>(buf2, wc + 2 * 36864, bg + 192, bb + 192, bm + 192, bv + 192, pre3);
  k_lifpool<16, true><<<128, 256, 0, stream>>>(pre3, buf3);

  k_conv<8, 2><<<128, 256, 0, stream>>>(buf3, wc + 3 * 36864, bg + 256, bb + 256, bm + 256, bv + 256, pre4);
  k_lifpool<8, false><<<32, 256, 0, stream>>>(pre4, buf4);

  k_fc1<<<512, 256, 0, stream>>>(buf4, w1, s1);
  k_fc2<<<220, 256, 0, stream>>>(s1, w2, s2);
  k_acc<<<1, 128, 0, stream>>>(s2, out);
}